// Round 3
// baseline (510.753 us; speedup 1.0000x reference)
//
#include <hip/hip_runtime.h>
#include <math.h>

// Problem constants (fixed by the reference: B=16, C=256, H=W=128, K=7)
#define HW      128
#define PLANE   16384                 // 128*128
#define CHS     256
#define BATCH   16
#define CSTRIDE 16384                 // plane stride in floats
#define BSTRIDE (256 * 16384)         // batch stride in floats = 4194304
#define CHUNK_B 4                     // batches per chunk: x-chunk (64 MiB) + out-chunk
                                      // (64 MiB NT, minimal alloc) + planes < 256 MiB L3
                                      // -> the mul pass re-reads x from L3, not HBM.

typedef float vf4 __attribute__((ext_vector_type(4)));   // for __builtin_nontemporal_store

// ---------------------------------------------------------------------------
// Kernel 1: channel-wise max + mean over C=256 for batches [b0, b0+CHUNK_B)
// Grid: 512 blocks x 256 threads.
//   Each block: 32 float4 spatial chunks (sc = tid & 31) x 8 channel groups
//   (cg = tid >> 5, 32 channels each). unroll 8 -> 8 loads in flight/thread.
// ---------------------------------------------------------------------------
__global__ __launch_bounds__(256) void reduce_kernel(
    const float* __restrict__ x, float* __restrict__ pmax, float* __restrict__ pavg,
    int b0)
{
    const int tid = threadIdx.x;
    const int sc  = tid & 31;
    const int cg  = tid >> 5;                  // 0..7
    const int g   = blockIdx.x * 32 + sc;      // chunk-local float4 id, 0..16383
    const int b   = b0 + (g >> 12);            // 4096 float4 per batch plane
    const int sp  = (g & 4095) << 2;           // float offset within plane

    const float* xp = x + (size_t)b * BSTRIDE + sp + (size_t)(cg << 5) * CSTRIDE;

    float4 vmax = make_float4(-INFINITY, -INFINITY, -INFINITY, -INFINITY);
    float4 vsum = make_float4(0.f, 0.f, 0.f, 0.f);

    #pragma unroll 8
    for (int c = 0; c < 32; ++c) {
        const float4 v = *(const float4*)(xp + (size_t)c * CSTRIDE);
        vmax.x = fmaxf(vmax.x, v.x); vmax.y = fmaxf(vmax.y, v.y);
        vmax.z = fmaxf(vmax.z, v.z); vmax.w = fmaxf(vmax.w, v.w);
        vsum.x += v.x; vsum.y += v.y; vsum.z += v.z; vsum.w += v.w;
    }

    __shared__ float4 smax[256];
    __shared__ float4 ssum[256];
    smax[tid] = vmax;
    ssum[tid] = vsum;
    __syncthreads();

    if (tid < 32) {
        float4 m = smax[tid];
        float4 s = ssum[tid];
        #pragma unroll
        for (int j = 1; j < 8; ++j) {
            const float4 mj = smax[tid + 32 * j];
            const float4 sj = ssum[tid + 32 * j];
            m.x = fmaxf(m.x, mj.x); m.y = fmaxf(m.y, mj.y);
            m.z = fmaxf(m.z, mj.z); m.w = fmaxf(m.w, mj.w);
            s.x += sj.x; s.y += sj.y; s.z += sj.z; s.w += sj.w;
        }
        const float inv = 1.0f / 256.0f;
        s.x *= inv; s.y *= inv; s.z *= inv; s.w *= inv;
        const int gg = blockIdx.x * 32 + tid;          // chunk-local float4 id
        const int bb = b0 + (gg >> 12);
        const int ss = (gg & 4095) << 2;
        *(float4*)(pmax + (size_t)bb * PLANE + ss) = m;
        *(float4*)(pavg + (size_t)bb * PLANE + ss) = s;
    }
}

// ---------------------------------------------------------------------------
// Kernel 2: 7x7 SAME conv on [max, avg] planes -> hsigmoid -> gate plane.
// Tiny: reads 512 KiB L2-resident planes, writes 256 KiB gate per chunk.
// Grid: CHUNK_B*128 blocks x 128 threads, one block per (b, h) row.
// ---------------------------------------------------------------------------
__global__ __launch_bounds__(128) void conv_gate_kernel(
    const float* __restrict__ pmax, const float* __restrict__ pavg,
    const float* __restrict__ cw, const float* __restrict__ cb,
    float* __restrict__ gate, int b0)
{
    __shared__ float sw[98];                      // conv_w: [2][7][7]
    const int tid = threadIdx.x;
    if (tid < 98) sw[tid] = cw[tid];
    const int b = b0 + (blockIdx.x >> 7);
    const int h = blockIdx.x & 127;
    __syncthreads();

    const int w = tid;
    float acc = cb[0];
    const float* pm = pmax + (size_t)b * PLANE;
    const float* pa = pavg + (size_t)b * PLANE;
    #pragma unroll
    for (int ky = 0; ky < 7; ++ky) {
        const int hh = h + ky - 3;
        if (hh >= 0 && hh < HW) {
            const float* prm = pm + hh * HW;
            const float* pra = pa + hh * HW;
            #pragma unroll
            for (int kx = 0; kx < 7; ++kx) {
                const int ww = w + kx - 3;
                if (ww >= 0 && ww < HW) {
                    acc = fmaf(sw[ky * 7 + kx],      prm[ww], acc);
                    acc = fmaf(sw[49 + ky * 7 + kx], pra[ww], acc);
                }
            }
        }
    }
    // hsigmoid: clip(acc+3, 0, 6) / 6
    gate[(size_t)b * PLANE + h * HW + w] =
        fminf(fmaxf(acc + 3.0f, 0.0f), 6.0f) * (1.0f / 6.0f);
}

// ---------------------------------------------------------------------------
// Kernel 3: out = x * gate (broadcast over channels), pure streaming.
// Grid: 1024 blocks x 256 threads (4 blocks/CU). Thread -> one spatial float4
// (sc) + channel phase (cp, 0..15); gate float4 is loop-invariant (loaded
// once); 16 channel iterations, NT stores (out is never re-read).
// ---------------------------------------------------------------------------
__global__ __launch_bounds__(256) void mul_kernel(
    const float* __restrict__ x, const float* __restrict__ gate,
    float* __restrict__ out, int b0)
{
    const int gt = blockIdx.x * 256 + threadIdx.x;   // 0..262143
    const int sc = gt & 16383;                       // chunk-local spatial float4 id
    const int cp = gt >> 14;                         // channel phase 0..15
    const int b  = b0 + (sc >> 12);
    const int sp = (sc & 4095) << 2;                 // float offset within plane

    const float4 g4 = *(const float4*)(gate + (size_t)b * PLANE + sp);
    const size_t base = (size_t)b * BSTRIDE + sp;

    #pragma unroll 4
    for (int c = cp; c < CHS; c += 16) {
        const size_t off = base + (size_t)c * CSTRIDE;
        const float4 v = *(const float4*)(x + off);
        vf4 r;
        r.x = v.x * g4.x; r.y = v.y * g4.y; r.z = v.z * g4.z; r.w = v.w * g4.w;
        __builtin_nontemporal_store(r, (vf4*)(out + off));
    }
}

extern "C" void kernel_launch(void* const* d_in, const int* in_sizes, int n_in,
                              void* d_out, int out_size, void* d_ws, size_t ws_size,
                              hipStream_t stream)
{
    const float* x  = (const float*)d_in[0];   // [16,256,128,128] fp32
    const float* cw = (const float*)d_in[1];   // [1,2,7,7] fp32
    const float* cb = (const float*)d_in[2];   // [1] fp32
    float* out = (float*)d_out;

    float* pmax = (float*)d_ws;                        // [16,128,128]
    float* pavg = pmax + (size_t)BATCH * PLANE;        // [16,128,128]
    float* gate = pavg + (size_t)BATCH * PLANE;        // [16,128,128]

    // Stream-ordered per-chunk triplets: reduce(chunk) pulls the x-chunk into
    // L3; conv_gate is tiny; mul(chunk) re-reads x from L3 and streams out.
    for (int b0 = 0; b0 < BATCH; b0 += CHUNK_B) {
        reduce_kernel<<<512, 256, 0, stream>>>(x, pmax, pavg, b0);
        conv_gate_kernel<<<CHUNK_B * 128, 128, 0, stream>>>(pmax, pavg, cw, cb, gate, b0);
        mul_kernel<<<1024, 256, 0, stream>>>(x, gate, out, b0);
    }
}

// Round 4
// 485.671 us; speedup vs baseline: 1.0516x; 1.0516x over previous
//
#include <hip/hip_runtime.h>
#include <math.h>

// Problem constants (fixed by the reference: B=16, C=256, H=W=128, K=7)
#define HW      128
#define PLANE   16384                 // 128*128
#define CHS     256
#define BATCH   16
#define CSTRIDE 16384                 // plane stride in floats
#define BSTRIDE (256 * 16384)         // batch stride in floats = 4194304
#define CHUNK_B 8                     // batches per chunk: x-chunk (128 MiB) + planes
                                      // (1 MiB) < 256 MiB L3 (out is NT, bypasses L3)
                                      // -> the mul phase re-reads x from L3, not HBM.
                                      // 2 chunks x 2 kernels = 4 launches total.

typedef float vf4 __attribute__((ext_vector_type(4)));   // for __builtin_nontemporal_store

// ---------------------------------------------------------------------------
// Kernel 1: channel-wise max + mean over C=256 for batches [b0, b0+CHUNK_B)
// Grid: CHUNK_B*128 = 1024 blocks x 256 threads (4 blocks/CU).
//   Each block: 32 float4 spatial chunks (sc = tid & 31) x 8 channel groups
//   (cg = tid >> 5, 32 channels each). unroll 8 -> 8 loads in flight/thread.
// ---------------------------------------------------------------------------
__global__ __launch_bounds__(256) void reduce_kernel(
    const float* __restrict__ x, float* __restrict__ pmax, float* __restrict__ pavg,
    int b0)
{
    const int tid = threadIdx.x;
    const int sc  = tid & 31;
    const int cg  = tid >> 5;                  // 0..7
    const int g   = blockIdx.x * 32 + sc;      // chunk-local float4 id
    const int b   = b0 + (g >> 12);            // 4096 float4 per batch plane
    const int sp  = (g & 4095) << 2;           // float offset within plane

    const float* xp = x + (size_t)b * BSTRIDE + sp + (size_t)(cg << 5) * CSTRIDE;

    float4 vmax = make_float4(-INFINITY, -INFINITY, -INFINITY, -INFINITY);
    float4 vsum = make_float4(0.f, 0.f, 0.f, 0.f);

    #pragma unroll 8
    for (int c = 0; c < 32; ++c) {
        const float4 v = *(const float4*)(xp + (size_t)c * CSTRIDE);
        vmax.x = fmaxf(vmax.x, v.x); vmax.y = fmaxf(vmax.y, v.y);
        vmax.z = fmaxf(vmax.z, v.z); vmax.w = fmaxf(vmax.w, v.w);
        vsum.x += v.x; vsum.y += v.y; vsum.z += v.z; vsum.w += v.w;
    }

    __shared__ float4 smax[256];
    __shared__ float4 ssum[256];
    smax[tid] = vmax;
    ssum[tid] = vsum;
    __syncthreads();

    if (tid < 32) {
        float4 m = smax[tid];
        float4 s = ssum[tid];
        #pragma unroll
        for (int j = 1; j < 8; ++j) {
            const float4 mj = smax[tid + 32 * j];
            const float4 sj = ssum[tid + 32 * j];
            m.x = fmaxf(m.x, mj.x); m.y = fmaxf(m.y, mj.y);
            m.z = fmaxf(m.z, mj.z); m.w = fmaxf(m.w, mj.w);
            s.x += sj.x; s.y += sj.y; s.z += sj.z; s.w += sj.w;
        }
        const float inv = 1.0f / 256.0f;
        s.x *= inv; s.y *= inv; s.z *= inv; s.w *= inv;
        const int gg = blockIdx.x * 32 + tid;          // chunk-local float4 id
        const int bb = b0 + (gg >> 12);
        const int ss = (gg & 4095) << 2;
        *(float4*)(pmax + (size_t)bb * PLANE + ss) = m;
        *(float4*)(pavg + (size_t)bb * PLANE + ss) = s;
    }
}

// ---------------------------------------------------------------------------
// Kernel 2: 7x7 SAME conv on [max, avg] planes -> hsigmoid gate -> x * gate
// for batches [b0, b0+CHUNK_B). Grid: CHUNK_B*128 = 1024 blocks x 256 threads,
// one block per (b, h) row.
//   Gate phase: ALL 256 threads — 2 threads per pixel, one per plane (49 taps
//   each, halves the serialized L2-load chain vs 98), LDS-combined.
//   Stream phase: 32 float4-iters/thread, unroll 8, NT stores (out is
//   write-once; bypassing L3 preserves the x-chunk for re-reads).
// ---------------------------------------------------------------------------
__global__ __launch_bounds__(256) void gate_mul_kernel(
    const float* __restrict__ x,
    const float* __restrict__ pmax, const float* __restrict__ pavg,
    const float* __restrict__ cw, const float* __restrict__ cb,
    float* __restrict__ out, int b0)
{
    __shared__ float sw[98];                      // conv_w: [2][7][7]
    __shared__ float part[256];
    __shared__ __align__(16) float sgate[HW];

    const int tid = threadIdx.x;
    if (tid < 98) sw[tid] = cw[tid];
    const int b = b0 + (blockIdx.x >> 7);
    const int h = blockIdx.x & 127;
    __syncthreads();

    {
        const int w  = tid & 127;
        const int pl = tid >> 7;                  // 0 = max plane, 1 = avg plane (wave-uniform)
        const float* pp = (pl ? pavg : pmax) + (size_t)b * PLANE;
        const float* wt = sw + pl * 49;
        float acc = 0.f;
        #pragma unroll
        for (int ky = 0; ky < 7; ++ky) {
            const int hh = h + ky - 3;
            if (hh >= 0 && hh < HW) {
                const float* pr = pp + hh * HW;
                #pragma unroll
                for (int kx = 0; kx < 7; ++kx) {
                    const int ww = w + kx - 3;
                    if (ww >= 0 && ww < HW)
                        acc = fmaf(wt[ky * 7 + kx], pr[ww], acc);
                }
            }
        }
        part[tid] = acc;
    }
    __syncthreads();

    if (tid < HW) {
        const float acc = part[tid] + part[tid + 128] + cb[0];
        // hsigmoid: clip(acc+3, 0, 6) / 6
        sgate[tid] = fminf(fmaxf(acc + 3.0f, 0.0f), 6.0f) * (1.0f / 6.0f);
    }
    __syncthreads();

    const int wc   = tid & 31;   // float4 chunk within the 128-wide row
    const int csub = tid >> 5;   // 0..7 channel phase
    const float4 g4 = *(const float4*)(sgate + wc * 4);
    const size_t rowbase = (size_t)b * BSTRIDE + (size_t)h * HW + wc * 4;

    #pragma unroll 8
    for (int c = csub; c < CHS; c += 8) {
        const size_t off = rowbase + (size_t)c * CSTRIDE;
        const float4 v = *(const float4*)(x + off);
        vf4 r;
        r.x = v.x * g4.x; r.y = v.y * g4.y; r.z = v.z * g4.z; r.w = v.w * g4.w;
        __builtin_nontemporal_store(r, (vf4*)(out + off));
    }
}

extern "C" void kernel_launch(void* const* d_in, const int* in_sizes, int n_in,
                              void* d_out, int out_size, void* d_ws, size_t ws_size,
                              hipStream_t stream)
{
    const float* x  = (const float*)d_in[0];   // [16,256,128,128] fp32
    const float* cw = (const float*)d_in[1];   // [1,2,7,7] fp32
    const float* cb = (const float*)d_in[2];   // [1] fp32
    float* out = (float*)d_out;

    float* pmax = (float*)d_ws;                        // [16,128,128]
    float* pavg = pmax + (size_t)BATCH * PLANE;        // [16,128,128]

    // Stream-ordered per-chunk pairs: reduce(chunk) pulls the x-chunk into L3,
    // gate_mul(chunk) re-reads it from L3 and streams out with NT stores.
    for (int b0 = 0; b0 < BATCH; b0 += CHUNK_B) {
        reduce_kernel<<<CHUNK_B * 128, 256, 0, stream>>>(x, pmax, pavg, b0);
        gate_mul_kernel<<<CHUNK_B * 128, 256, 0, stream>>>(x, pmax, pavg, cw, cb, out, b0);
    }
}